// Round 1
// baseline (90.340 us; speedup 1.0000x reference)
//
#include <hip/hip_runtime.h>

#define SPAN_W 32

// Kernel 1: global_logits[b,t] = dot(seq[b,t,:], att_w) + att_b
// One wave (64 lanes) per row; D=768 -> 192 float4 -> 3 float4 per lane.
__global__ __launch_bounds__(256) void logits_kernel(
    const float* __restrict__ seq,
    const float* __restrict__ att_w,
    const float* __restrict__ att_b,
    float* __restrict__ logits,
    int BT, int D)
{
    int row  = blockIdx.x * 4 + (threadIdx.x >> 6);
    int lane = threadIdx.x & 63;
    if (row >= BT) return;

    const float4* p  = reinterpret_cast<const float4*>(seq + (size_t)row * D);
    const float4* w4 = reinterpret_cast<const float4*>(att_w);
    int d4 = D >> 2;                      // 192
    float acc = 0.f;
    for (int k = lane; k < d4; k += 64) { // 3 iters
        float4 v = p[k];
        float4 w = w4[k];
        acc += v.x * w.x + v.y * w.y + v.z * w.z + v.w * w.w;
    }
    #pragma unroll
    for (int off = 32; off > 0; off >>= 1)
        acc += __shfl_xor(acc, off);
    if (lane == 0)
        logits[row] = acc + att_b[0];
}

// Kernel 2: one block per span. Lanes 0..31 compute the masked softmax
// exactly as the reference (masked logits contribute z=0 to the softmax
// denominator; then att*mask, renorm with +1e-13). Then all 192 threads
// accumulate the weighted sum over valid positions, one float4 per thread.
__global__ __launch_bounds__(192) void span_kernel(
    const float* __restrict__ seq,     // (B,T,D)
    const int*   __restrict__ spans,   // (B,N,2)
    const float* __restrict__ logits,  // (B,T)
    float*       __restrict__ out,     // (B,N,D)
    int T, int D, int N)
{
    int span = blockIdx.x;             // b*N + n
    int b    = span / N;

    int s0 = spans[(size_t)span * 2 + 0];
    int e0 = spans[(size_t)span * 2 + 1];   // inclusive end
    int width = e0 - s0;
    (void)s0;

    __shared__ float att[SPAN_W];

    int tid = threadIdx.x;
    if (tid < SPAN_W) {
        int r   = tid;
        int raw = e0 - r;
        bool m  = (r <= width) && (raw >= 0);
        int idx = raw > 0 ? raw : 0;
        // masked position: z = logit * 0 = 0 (still enters softmax denom)
        float z = m ? logits[(size_t)b * T + idx] : 0.0f;

        float zmax = z;
        #pragma unroll
        for (int off = 16; off > 0; off >>= 1)
            zmax = fmaxf(zmax, __shfl_xor(zmax, off));
        float e = __expf(z - zmax);
        float S = e;
        #pragma unroll
        for (int off = 16; off > 0; off >>= 1)
            S += __shfl_xor(S, off);
        float t = m ? (e / S) : 0.0f;   // softmax * mask
        float Tt = t;
        #pragma unroll
        for (int off = 16; off > 0; off >>= 1)
            Tt += __shfl_xor(Tt, off);
        att[r] = t / (Tt + 1e-13f);
    }
    __syncthreads();

    int nvalid = width + 1;
    if (nvalid > SPAN_W) nvalid = SPAN_W;
    if (nvalid < 1) nvalid = 1;

    float4 acc = make_float4(0.f, 0.f, 0.f, 0.f);
    for (int w = 0; w < nvalid; ++w) {
        float a  = att[w];
        int  idx = e0 - w;
        if (idx < 0) idx = 0;
        const float4* p =
            reinterpret_cast<const float4*>(seq + ((size_t)b * T + idx) * D);
        float4 v = p[tid];               // tid in [0,192) covers 768 floats
        acc.x += a * v.x;
        acc.y += a * v.y;
        acc.z += a * v.z;
        acc.w += a * v.w;
    }
    reinterpret_cast<float4*>(out + (size_t)span * D)[tid] = acc;
}

extern "C" void kernel_launch(void* const* d_in, const int* in_sizes, int n_in,
                              void* d_out, int out_size, void* d_ws, size_t ws_size,
                              hipStream_t stream)
{
    const float* seq   = (const float*)d_in[0];
    const int*   spans = (const int*)  d_in[1];
    const float* att_w = (const float*)d_in[2];
    const float* att_b = (const float*)d_in[3];
    float*       out   = (float*)d_out;
    float*       lg    = (float*)d_ws;     // B*T floats = 32 KB

    const int D  = in_sizes[2];            // 768 (att_w is D x 1)
    const int B  = 4;                      // fixed per reference setup_inputs
    const int BT = in_sizes[0] / D;        // 8192
    const int T  = BT / B;                 // 2048
    const int BN = out_size / D;           // 2048
    const int N  = BN / B;                 // 512

    // Kernel 1: 4 rows per 256-thread block (one wave per row)
    int blocks1 = (BT + 3) / 4;
    logits_kernel<<<blocks1, 256, 0, stream>>>(seq, att_w, att_b, lg, BT, D);

    // Kernel 2: one block per span
    span_kernel<<<BN, 192, 0, stream>>>(seq, spans, lg, out, T, D, N);
}